// Round 1
// 375.575 us; speedup vs baseline: 1.0664x; 1.0664x over previous
//
#include <hip/hip_runtime.h>
#include <cstdint>
#include <cstddef>

typedef __bf16 bf16x8 __attribute__((ext_vector_type(8)));
typedef float f32x4 __attribute__((ext_vector_type(4)));
typedef unsigned short ushortx8 __attribute__((ext_vector_type(8)));
typedef unsigned short ushortx4 __attribute__((ext_vector_type(4)));

// float -> bf16, round-half-up
__device__ __forceinline__ unsigned short f2bf(float f) {
  union { float f; unsigned int u; } v; v.f = f;
  return (unsigned short)((v.u + 0x8000u) >> 16);
}

// GELU via sigmoid identity (verified in prior rounds)
__device__ __forceinline__ float gelu_s(float x) {
  float x2 = x * x;
  float p = __builtin_fmaf(x2, -0.10294324f, -2.30220819f);
  float e = __builtin_amdgcn_exp2f(x * p);
  return x * __builtin_amdgcn_rcpf(1.0f + e);
}

// async global->LDS, 16B/lane. LDS dest is wave-uniform base + lane*16.
#define GLOAD16(gsrc, ldst)                                                  \
  __builtin_amdgcn_global_load_lds(                                          \
      (const __attribute__((address_space(1))) unsigned int*)(gsrc),         \
      (__attribute__((address_space(3))) unsigned int*)(uintptr_t)(          \
          (char*)(ldst)),                                                    \
      16, 0, 0)

// Swizzled tile: 16B chunk (row R, col8 C in [0,8)) at
// (R>>5)*4096 + ((R&31)*8 + (C ^ (R&7)))*16. Staging lane tid sources col8
// (tid&7)^((tid>>3)&7); 16-row fragment reads hit all 8 bank quads.
#define SWZ_FRAG(base, R, C8)                                                \
  (*(const bf16x8*)((base) + (((R) >> 5) * 4096) +                           \
                    ((((R)&31) * 8 + ((C8) ^ ((R)&7))) * 16)))

// ---------------------------------------------------------------------------
// Conversion: z -> bf16 (dense float4 loads); W1[g,d,h] -> W1t[g,h,d] bf16;
// Wc[d,g] -> Wct[g,d] bf16
// ---------------------------------------------------------------------------
__global__ __launch_bounds__(256) void k_convert(
    const float* __restrict__ z, const float* __restrict__ W1,
    const float* __restrict__ Wc, unsigned short* __restrict__ zb,
    unsigned short* __restrict__ w1t, unsigned short* __restrict__ wct) {
  int bid = blockIdx.x;
  int tid = threadIdx.x;
  if (bid < 8192) {
    // 8192 blocks x 256 threads x 4 float4 = 2^23 float4 = all of z.
    // Every load instruction is lane-dense 16B; store is lane-dense 8B.
    const float4* z4 = (const float4*)z;
    size_t base = (size_t)bid * 1024 + tid;
#pragma unroll
    for (int it = 0; it < 4; ++it) {
      size_t i4 = base + (size_t)it * 256;
      float4 a = z4[i4];
      ushortx4 r;
      r[0] = f2bf(a.x); r[1] = f2bf(a.y); r[2] = f2bf(a.z); r[3] = f2bf(a.w);
      *(ushortx4*)(zb + i4 * 4) = r;
    }
  } else if (bid < 8192 + 1024) {
    // W1 transpose via 32x32 LDS tile, both sides coalesced
    __shared__ float tile[32][33];
    int b = bid - 8192;
    int gg = b >> 6;
    int t = b & 63;  // 16 d-blk x 4 h-blk
    int d0 = (t >> 2) * 32;
    int h0 = (t & 3) * 32;
    int tx = tid & 31, ty = tid >> 5;
#pragma unroll
    for (int r = 0; r < 4; ++r) {
      int d = d0 + r * 8 + ty;
      tile[r * 8 + ty][tx] = W1[(gg << 16) + d * 128 + h0 + tx];
    }
    __syncthreads();
#pragma unroll
    for (int r = 0; r < 4; ++r) {
      int h = h0 + r * 8 + ty;
      w1t[(gg << 16) + h * 512 + d0 + tx] = f2bf(tile[tx][r * 8 + ty]);
    }
  } else {
#pragma unroll
    for (int j = 0; j < 32; ++j) {
      int i = j * 256 + tid;
      wct[(i & 15) * 512 + (i >> 4)] = f2bf(Wc[i]);
    }
  }
}

// ---------------------------------------------------------------------------
// Fused main kernel:
//   bid < 512  : logits+softmax block, 128 rows (unchanged)
//   bid >= 512 : expert block, 128 rows x 128 cols (ONE expert), 4 waves,
//                each wave 64x64 (4x4 of 16x16x32). Block order is m-major
//                with XCD chunking: virtual idx = (eb&7)*1024 + (eb>>3);
//                e = idx&15, m = idx>>4  => all 16 experts of one z-tile run
//                back-to-back on the same XCD (z fetched from HBM ~once,
//                W1t 2MB stays L2-hot).
// LDS: A 16KB | B 16KB | ylds 1KB  => ~34KB => 4 blocks/CU (16 waves/CU).
// ---------------------------------------------------------------------------
__global__ __launch_bounds__(256, 4) void k_main(
    const unsigned short* __restrict__ zb,   // [65536][512] bf16
    const unsigned short* __restrict__ w1t,  // [16][128][512] bf16
    const unsigned short* __restrict__ wct,  // [16][512] bf16
    const float* __restrict__ bc, const float* __restrict__ b1,
    const float* __restrict__ w2, const float* __restrict__ b2,
    float* __restrict__ out) {
  __shared__ alignas(16) char lds[16384 + 16384 + 1024];  // A | B | ylds
  const int tid = threadIdx.x;
  const int wq = tid >> 6;
  const int ln = tid & 63;
  const int l15 = ln & 15;
  const int l4 = ln >> 4;
  const int c8s = (((tid & 7) ^ ((tid >> 3) & 7))) * 8;
  char* ldsB = lds + 16384;

  if (blockIdx.x >= 512) {
    // ---------------- expert block: h = z_tile @ W1[e]^T, gelu, dot W2 ----
    const int eb = blockIdx.x - 512;                  // 0..8191
    const int idx = (eb & 7) * 1024 + (eb >> 3);      // XCD-chunked, m-major
    const int e = idx & 15;
    const int mbase = (idx >> 4) * 128;
    const unsigned short* ag = zb + (size_t)(mbase + (tid >> 3)) * 512 + c8s;
    const unsigned short* bg =
        w1t + e * 65536 + (tid >> 3) * 512 + c8s;
    const int wr = wq >> 1;   // row half of this wave
    const int wc = wq & 1;    // col half of this wave
    f32x4 acc[4][4] = {};
    for (int kt = 0; kt < 8; ++kt) {
      const int ko = kt * 64;
#pragma unroll
      for (int it = 0; it < 4; ++it)
        GLOAD16(ag + it * 32 * 512 + ko, lds + it * 4096 + tid * 16);
#pragma unroll
      for (int it = 0; it < 4; ++it)
        GLOAD16(bg + it * 32 * 512 + ko, ldsB + it * 4096 + tid * 16);
      __syncthreads();
#pragma unroll
      for (int ks = 0; ks < 2; ++ks) {
        bf16x8 af[4];
#pragma unroll
        for (int rt = 0; rt < 4; ++rt)
          af[rt] = SWZ_FRAG(lds, wr * 64 + rt * 16 + l15, ks * 4 + l4);
#pragma unroll
        for (int ct = 0; ct < 4; ++ct) {
          bf16x8 bfv = SWZ_FRAG(ldsB, wc * 64 + ct * 16 + l15, ks * 4 + l4);
#pragma unroll
          for (int rt = 0; rt < 4; ++rt)
            acc[rt][ct] = __builtin_amdgcn_mfma_f32_16x16x32_bf16(
                af[rt], bfv, acc[rt][ct], 0, 0, 0);
        }
      }
      __syncthreads();
    }
    // epilogue: partial y over this wave's 64 cols, cross-wave combine
    float b1v[4], w2v[4];
#pragma unroll
    for (int ct = 0; ct < 4; ++ct) {
      int n = wc * 64 + ct * 16 + l15;
      b1v[ct] = b1[e * 128 + n];
      w2v[ct] = w2[e * 128 + n];
    }
    float* ylds = (float*)(lds + 32768);  // [4 waves][64 rows]
#pragma unroll
    for (int rt = 0; rt < 4; ++rt) {
#pragma unroll
      for (int i = 0; i < 4; ++i) {
        float s = 0.0f;
#pragma unroll
        for (int ct = 0; ct < 4; ++ct)
          s += gelu_s(acc[rt][ct][i] + b1v[ct]) * w2v[ct];
#pragma unroll
        for (int off = 1; off < 16; off <<= 1)
          s += __shfl_xor(s, off, 16);
        if (l15 == 0) ylds[wq * 64 + rt * 16 + l4 * 4 + i] = s;
      }
    }
    __syncthreads();
    if (tid < 128) {
      int rl = tid & 63, half = tid >> 6;  // half == wr
      float y = ylds[half * 128 + rl] + ylds[half * 128 + 64 + rl] + b2[e];
      out[(size_t)2097152 + (size_t)(mbase + half * 64 + rl) * 16 + e] = y;
    }
  } else {
    // ---------------- logits block: logits = z_tile @ Wc + bc, softmax ----
    const int mbase = blockIdx.x * 128;
    const unsigned short* ag = zb + (size_t)(mbase + (tid >> 3)) * 512 + c8s;
    const unsigned short* wb = wct + l15 * 512 + l4 * 8;  // direct, L2-hot
    f32x4 acc2[2] = {};
    for (int kt = 0; kt < 8; ++kt) {
      const int ko = kt * 64;
#pragma unroll
      for (int it = 0; it < 4; ++it)
        GLOAD16(ag + it * 32 * 512 + ko, lds + it * 4096 + tid * 16);
      bf16x8 bfr0 = *(const bf16x8*)(wb + ko);
      bf16x8 bfr1 = *(const bf16x8*)(wb + ko + 32);
      __syncthreads();
#pragma unroll
      for (int rt = 0; rt < 2; ++rt) {
        bf16x8 a0 = SWZ_FRAG(lds, wq * 32 + rt * 16 + l15, l4);
        acc2[rt] = __builtin_amdgcn_mfma_f32_16x16x32_bf16(a0, bfr0, acc2[rt],
                                                           0, 0, 0);
        bf16x8 a1 = SWZ_FRAG(lds, wq * 32 + rt * 16 + l15, 4 + l4);
        acc2[rt] = __builtin_amdgcn_mfma_f32_16x16x32_bf16(a1, bfr1, acc2[rt],
                                                           0, 0, 0);
      }
      __syncthreads();
    }
    float bcv = bc[l15];
#pragma unroll
    for (int rt = 0; rt < 2; ++rt) {
#pragma unroll
      for (int i = 0; i < 4; ++i) {
        int row = wq * 32 + rt * 16 + l4 * 4 + i;
        float lg = acc2[rt][i] + bcv;
        float mx = lg;
#pragma unroll
        for (int off = 1; off < 16; off <<= 1)
          mx = fmaxf(mx, __shfl_xor(mx, off, 16));
        float ex = __expf(lg - mx);
        float sm = ex;
#pragma unroll
        for (int off = 1; off < 16; off <<= 1)
          sm += __shfl_xor(sm, off, 16);
        size_t ro = (size_t)(mbase + row) * 16 + l15;
        out[ro] = lg;                  // logits
        out[1048576 + ro] = ex / sm;   // p_g
      }
    }
  }
}

// ---------------------------------------------------------------------------
extern "C" void kernel_launch(void* const* d_in, const int* in_sizes, int n_in,
                              void* d_out, int out_size, void* d_ws,
                              size_t ws_size, hipStream_t stream) {
  const float* z = (const float*)d_in[0];
  const float* Wc = (const float*)d_in[1];
  const float* bc = (const float*)d_in[2];
  const float* W1 = (const float*)d_in[3];
  const float* b1 = (const float*)d_in[4];
  const float* W2 = (const float*)d_in[5];
  const float* b2 = (const float*)d_in[6];
  float* out = (float*)d_out;

  unsigned short* zb = (unsigned short*)d_ws;            // 64 MB
  unsigned short* w1t = zb + (size_t)65536 * 512;        // 2 MB
  unsigned short* wct = w1t + (size_t)16 * 128 * 512;    // 16 KB

  k_convert<<<8192 + 1024 + 1, 256, 0, stream>>>(z, W1, Wc, zb, w1t, wct);
  k_main<<<512 + 8192, 256, 0, stream>>>(zb, w1t, wct, bc, b1, W2, b2, out);
}